// Round 2
// baseline (475.313 us; speedup 1.0000x reference)
//
#include <hip/hip_runtime.h>
#include <math.h>

#define BB 256
#define NN 200000
#define DD 128
#define INV_T 14.285714285714286f   // 1/0.07

// Wave-private hit lists: CAPW entries per wave (4 waves/block, 12 KB LDS so
// 8 blocks/CU co-reside = 32 waves/CU, full occupancy).
// Flush invariant: between two consecutive wave-local count checks, a wave
// pushes <= 512 entries:
//   int32 path: one check per iter, 2 uint4 x 4 ints x 64 lanes = 512
//   bool  path: uint4/lane but a check after EACH 8-byte half -> 512
// The check is a wave-uniform volatile LDS read (one wave's LDS ops complete
// in program order, so it sees all of this wave's atomics; no barrier).
// Flushing when cnt >= CAPW-512 guarantees every pos < CAPW.
#define CAPW 768
#define FLUSHW (CAPW - 512)

// ---------------------------------------------------------------------------
// d_ws layout (32-bit word offsets). Every word is plain-stored by la_init
// before la_fused reads/RMWs it (kernel-boundary coherence) -> no extra pass.
//   [0   ..255 ]  votes: per-block dtype verdicts (bool-byte mode iff any != 0)
//   [256 ..511 ]  scale[b] = INV_T / ||codes[b]||
//   [512 ..767 ]  d1[b]  (atomicAdd-accumulated background density)
//   [768 ..1023]  d2[b]  (atomicAdd-accumulated intersect density)
//   [1024]        done-counter for the fused grid (last block computes loss)
// ---------------------------------------------------------------------------
#define WS_VOTE  0
#define WS_SCALE 256
#define WS_D1    512
#define WS_D2    768
#define WS_DONE  1024

// Kernel 1: dtype detect (per-block plain-store votes) + per-row scale +
// zero-init of d1/d2/done. Grid = 256 blocks (one row each); detect word
// i = b*256+t covers the first 50000 words of mask_bg exactly once
// (200000 bytes: in-bounds under both interpretations). Packed bool bytes
// give word values > 1; int32 bools are strictly 0/1.
__global__ __launch_bounds__(256) void la_init(const float* __restrict__ codes,
                                               const unsigned* __restrict__ mbg_w,
                                               unsigned* __restrict__ wsu) {
    __shared__ float s_red[4];
    __shared__ unsigned s_any[4];
    const int t = threadIdx.x;
    const unsigned lane = (unsigned)(t & 63);
    const unsigned wid = (unsigned)(t >> 6);
    const int b = blockIdx.x;

    const unsigned i = (unsigned)(b * 256 + t);
    const int any = (i < 50000u) && (mbg_w[i] > 1u);
    const unsigned long long bal = __ballot(any);
    if (lane == 0) s_any[wid] = (bal != 0ull) ? 1u : 0u;

    // scale: same reduce tree as before (bit-exact)
    float c = (t < DD) ? codes[b * DD + t] : 0.f;
    float sq = c * c;
#pragma unroll
    for (int off = 32; off > 0; off >>= 1) sq += __shfl_down(sq, off, 64);
    if (lane == 0) s_red[wid] = sq;
    __syncthreads();
    if (t == 0) {
        float* wsf = (float*)wsu;
        wsf[WS_SCALE + b] = rsqrtf(s_red[0] + s_red[1] + s_red[2] + s_red[3]) * INV_T;
        wsu[WS_VOTE + b] = s_any[0] | s_any[1] | s_any[2] | s_any[3];
        wsf[WS_D1 + b] = 0.f;
        wsf[WS_D2 + b] = 0.f;
        if (b == 0) wsu[WS_DONE] = 0u;
    }
}

// Wave-cooperative hit processing: 64-lane dot (float2/lane) against the bank
// row; the (wave-uniform-address) mask_int load is issued alongside the bank
// row load so both latencies overlap. Only lane 0 accumulates.
__device__ __forceinline__ void process_wave(const float2* __restrict__ bank2,
                                             const unsigned* __restrict__ m32,
                                             const unsigned char* __restrict__ m8,
                                             const unsigned* __restrict__ ent,
                                             int cnt, int flag, int b,
                                             float2 cv, float scale,
                                             unsigned lane, float& l1, float& l2) {
    for (int i = 0; i < cnt; ++i) {
        const unsigned n = ent[i];
        const float2 bv = bank2[(size_t)n * 64u + lane];
        const unsigned im = (flag == 0) ? m32[(size_t)b * NN + n]
                                        : (unsigned)m8[(size_t)b * NN + n];
        float d = fmaf(cv.x, bv.x, cv.y * bv.y);
#pragma unroll
        for (int off = 32; off > 0; off >>= 1) d += __shfl_down(d, off, 64);
        if (lane == 0) {
            const float e = __expf(d * scale);
            l1 += e;
            if (im) l2 += e;
        }
    }
}

// Fused scan + gather + (last block) final reduce. Block = (slice s, row b).
// Hit lists are wave-private: no barrier anywhere in the scan. The bool path
// loads uint4/lane with a depth-2 software pipeline (next iteration's load is
// issued before the current one is consumed, hiding one HBM round-trip).
__global__ __launch_bounds__(256) void la_fused(const float* __restrict__ codes,
                                                const float* __restrict__ bank,
                                                const void* __restrict__ mbg_v,
                                                const void* __restrict__ mint_v,
                                                unsigned* __restrict__ wsu,
                                                float* __restrict__ out) {
    __shared__ unsigned s_ent[4][CAPW];
    __shared__ unsigned s_cnt[4];
    __shared__ float s_red[8];
    __shared__ int s_last;

    const int t = threadIdx.x;
    const unsigned lane = (unsigned)(t & 63);
    const unsigned wid = (unsigned)(t >> 6);
    const int s = blockIdx.x;    // slice 0..7
    const int b = blockIdx.y;    // row 0..255

    // dtype flag from the 256 vote words (ballot -> wave-uniform, no barrier)
    const unsigned v4 = wsu[WS_VOTE + lane] | wsu[WS_VOTE + 64 + lane] |
                        wsu[WS_VOTE + 128 + lane] | wsu[WS_VOTE + 192 + lane];
    const int flag = (__ballot(v4 != 0u) != 0ull) ? 1 : 0;

    if (lane == 0) s_cnt[wid] = 0u;
    const float scale = ((const float*)wsu)[WS_SCALE + b];
    const float2 cv = ((const float2*)codes)[b * 64 + (int)lane];  // code frag in regs
    const float2* bank2 = (const float2*)bank;
    const unsigned* m32 = (const unsigned*)mint_v;
    const unsigned char* m8 = (const unsigned char*)mint_v;
    unsigned* ent = s_ent[wid];
    const int n_base = s * 25000;

    float l1 = 0.f, l2 = 0.f;

    if (flag == 0) {
        // int32 masks (fallback, unused in practice): slice = 6250 uint4;
        // 13 iters x 512 uint4, one flush check per iter (<=512 pushes).
        const uint4* row = (const uint4*)((const char*)mbg_v + (size_t)b * ((size_t)NN * 4)) + s * 6250;
        for (int it = 0; it < 13; ++it) {
            const int i0 = it * 512 + t;
            const int i1 = i0 + 256;
            uint4 v0 = make_uint4(0u, 0u, 0u, 0u), v1 = make_uint4(0u, 0u, 0u, 0u);
            if (i0 < 6250) v0 = row[i0];
            if (i1 < 6250) v1 = row[i1];
            const bool h0 = (v0.x | v0.y | v0.z | v0.w) != 0u;
            const bool h1 = (v1.x | v1.y | v1.z | v1.w) != 0u;
            if (__any((int)(h0 | h1))) {
                if (h0) {
                    const unsigned gw[4] = {v0.x, v0.y, v0.z, v0.w};
#pragma unroll
                    for (int j = 0; j < 4; ++j)
                        if (gw[j] != 0u) {
                            const unsigned pos = atomicAdd(&s_cnt[wid], 1u);
                            if (pos < CAPW) ent[pos] = (unsigned)(n_base + i0 * 4 + j);
                        }
                }
                if (h1) {
                    const unsigned gw[4] = {v1.x, v1.y, v1.z, v1.w};
#pragma unroll
                    for (int j = 0; j < 4; ++j)
                        if (gw[j] != 0u) {
                            const unsigned pos = atomicAdd(&s_cnt[wid], 1u);
                            if (pos < CAPW) ent[pos] = (unsigned)(n_base + i1 * 4 + j);
                        }
                }
                const int cnt = (int)*(volatile unsigned*)&s_cnt[wid];
                if (cnt >= FLUSHW) {                    // never in practice
                    process_wave(bank2, m32, m8, ent, cnt, flag, b, cv, scale, lane, l1, l2);
                    if (lane == 0) s_cnt[wid] = 0u;
                }
            }
        }
    } else {
        // bool-byte masks: row = 12500 uint4; slice = 1563 uint4 (last 1559).
        // 7 iters x 256 uint4, depth-2 pipeline; flush check per 8-byte half.
        const uint4* row4 = (const uint4*)((const char*)mbg_v + (size_t)b * NN);
        const int w0 = s * 1563;
        const int wend = (s == 7) ? 12500 : (w0 + 1563);
        uint4 cur = make_uint4(0u, 0u, 0u, 0u);
        { const int i0 = w0 + t; if (i0 < wend) cur = row4[i0]; }
        for (int it = 0; it < 7; ++it) {
            uint4 nxt = make_uint4(0u, 0u, 0u, 0u);
            if (it < 6) {
                const int in = w0 + (it + 1) * 256 + t;
                if (in < wend) nxt = row4[in];
            }
            const int ic = w0 + it * 256 + t;           // cur==0 if ic >= wend
            const bool hl = (cur.x | cur.y) != 0u;
            const bool hh = (cur.z | cur.w) != 0u;
            if (__any((int)(hl | hh))) {
                if (hl) {
                    const unsigned gw[2] = {cur.x, cur.y};
#pragma unroll
                    for (int j = 0; j < 8; ++j)
                        if (((gw[j >> 2] >> ((j & 3) * 8)) & 0xffu) != 0u) {
                            const unsigned pos = atomicAdd(&s_cnt[wid], 1u);
                            if (pos < CAPW) ent[pos] = (unsigned)(ic * 16 + j);
                        }
                }
                {
                    const int cnt = (int)*(volatile unsigned*)&s_cnt[wid];
                    if (cnt >= FLUSHW) {                // never in practice
                        process_wave(bank2, m32, m8, ent, cnt, flag, b, cv, scale, lane, l1, l2);
                        if (lane == 0) s_cnt[wid] = 0u;
                    }
                }
                if (hh) {
                    const unsigned gw[2] = {cur.z, cur.w};
#pragma unroll
                    for (int j = 0; j < 8; ++j)
                        if (((gw[j >> 2] >> ((j & 3) * 8)) & 0xffu) != 0u) {
                            const unsigned pos = atomicAdd(&s_cnt[wid], 1u);
                            if (pos < CAPW) ent[pos] = (unsigned)(ic * 16 + 8 + j);
                        }
                }
                {
                    const int cnt = (int)*(volatile unsigned*)&s_cnt[wid];
                    if (cnt >= FLUSHW) {                // never in practice
                        process_wave(bank2, m32, m8, ent, cnt, flag, b, cv, scale, lane, l1, l2);
                        if (lane == 0) s_cnt[wid] = 0u;
                    }
                }
            }
            cur = nxt;
        }
    }

    // ---- tail: drain this wave's list (lane 0 holds the partials)
    int cnt = (int)*(volatile unsigned*)&s_cnt[wid];
    if (cnt > CAPW) cnt = CAPW;
    process_wave(bank2, m32, m8, ent, cnt, flag, b, cv, scale, lane, l1, l2);

    if (lane == 0) { s_red[wid] = l1; s_red[4 + wid] = l2; }
    __syncthreads();
    float* wsf = (float*)wsu;
    if (t == 0) {
        atomicAdd(&wsf[WS_D1 + b], s_red[0] + s_red[1] + s_red[2] + s_red[3]);
        atomicAdd(&wsf[WS_D2 + b], s_red[4] + s_red[5] + s_red[6] + s_red[7]);
        // release: this block's d1/d2 adds complete before its done-increment
        __threadfence();
        const unsigned old = atomicAdd(&wsu[WS_DONE], 1u);
        s_last = (old == 8u * BB - 1u) ? 1 : 0;
    }
    __syncthreads();

    // ---- last block to finish computes the loss (replaces la_final launch).
    // d1/d2 reads via atomic RMW: serialized at the device coherent point, so
    // they observe every prior atomicAdd (all of which happened-before the
    // 2048th done-increment via each block's release fence).
    if (s_last) {
        const float d1v = atomicAdd(&wsf[WS_D1 + t], 0.f);
        const float d2v = atomicAdd(&wsf[WS_D2 + t], 0.f);
        float v = logf(d1v) - logf(d2v);
#pragma unroll
        for (int off = 32; off > 0; off >>= 1) v += __shfl_down(v, off, 64);
        if (lane == 0) s_red[wid] = v;
        __syncthreads();
        if (t == 0) out[0] = (s_red[0] + s_red[1] + s_red[2] + s_red[3]) / (float)BB;
    }
}

extern "C" void kernel_launch(void* const* d_in, const int* in_sizes, int n_in,
                              void* d_out, int out_size, void* d_ws, size_t ws_size,
                              hipStream_t stream) {
    const float* codes = (const float*)d_in[0];
    const float* bank  = (const float*)d_in[1];
    const void*  mbg   = d_in[2];
    const void*  mit   = d_in[3];

    unsigned* wsu = (unsigned*)d_ws;

    la_init<<<BB, 256, 0, stream>>>(codes, (const unsigned*)mbg, wsu);
    la_fused<<<dim3(8, BB), 256, 0, stream>>>(codes, bank, mbg, mit, wsu, (float*)d_out);
}

// Round 3
// 408.718 us; speedup vs baseline: 1.1629x; 1.1629x over previous
//
#include <hip/hip_runtime.h>
#include <math.h>

#define BB 256
#define NN 200000
#define DD 128
#define INV_T 14.285714285714286f   // 1/0.07

// Wave-private hit lists: CAPW entries per wave (4 waves/block, 12 KB LDS so
// 8 blocks/CU co-reside = 32 waves/CU, full occupancy).
// Flush invariant: between two consecutive wave-local count checks, a wave
// pushes <= 512 entries:
//   int32 path: one check per iter, 2 uint4 x 4 ints x 64 lanes = 512
//   bool  path: one check per iter, 1 uint2 x 8 bytes x 64 lanes = 512
// The check is a wave-uniform volatile LDS read (one wave's LDS ops complete
// in program order, so it sees all of this wave's atomics; no barrier).
// Flushing when cnt >= CAPW-512 guarantees every pos < CAPW.
//
// NOTE (R2 post-mortem): do NOT fuse the final reduce into this grid via
// done-counter + __threadfence(). The agent-scope fence's L2
// writeback/invalidate, fired once per block (2048x), thrashed sibling
// blocks' L2 (+45 MB refetch) and made la_fused latency-bound (157 us vs
// ~40 us). Separate tiny la_final launch is far cheaper.
#define CAPW 768
#define FLUSHW (CAPW - 512)

// ---------------------------------------------------------------------------
// d_ws layout (32-bit word offsets). Every word is plain-stored before it is
// read (votes/scale by la_init, partials by la_fused) -> NO zero-init pass.
//   [0   ..255 ]  votes: per-block dtype verdicts (bool-byte mode iff any != 0)
//   [256 ..511 ]  scale[b] = INV_T / ||codes[b]||
//   [512 ..2559]  P1[b*8+s]: per-(row,slice) background-density partials
//   [2560..4607]  P2[b*8+s]: intersect-density partials
// ---------------------------------------------------------------------------
#define WS_VOTE  0
#define WS_SCALE 256
#define WS_P1    512
#define WS_P2    2560

// Kernel 1: dtype detect (per-block plain-store votes) + per-row scale.
// Grid = 256 blocks (one row each); detect word i = b*256+t covers the first
// 50000 words of mask_bg exactly once (200000 bytes: in-bounds under both the
// int32 and packed-bool interpretations). Packed bool bytes give word values
// > 1; int32 bools are strictly 0/1.
__global__ __launch_bounds__(256) void la_init(const float* __restrict__ codes,
                                               const unsigned* __restrict__ mbg_w,
                                               unsigned* __restrict__ wsu) {
    __shared__ float s_red[4];
    __shared__ unsigned s_any[4];
    const int t = threadIdx.x;
    const unsigned lane = (unsigned)(t & 63);
    const unsigned wid = (unsigned)(t >> 6);
    const int b = blockIdx.x;

    const unsigned i = (unsigned)(b * 256 + t);
    const int any = (i < 50000u) && (mbg_w[i] > 1u);
    const unsigned long long bal = __ballot(any);
    if (lane == 0) s_any[wid] = (bal != 0ull) ? 1u : 0u;

    // scale: bit-exact replica of the original per-block prologue reduce tree
    float c = (t < DD) ? codes[b * DD + t] : 0.f;
    float sq = c * c;
#pragma unroll
    for (int off = 32; off > 0; off >>= 1) sq += __shfl_down(sq, off, 64);
    if (lane == 0) s_red[wid] = sq;
    __syncthreads();
    if (t == 0) {
        float* wsf = (float*)wsu;
        wsf[WS_SCALE + b] = rsqrtf(s_red[0] + s_red[1] + s_red[2] + s_red[3]) * INV_T;
        wsu[WS_VOTE + b] = s_any[0] | s_any[1] | s_any[2] | s_any[3];
    }
}

// Wave-cooperative hit processing: 64-lane dot (float2/lane) against the bank
// row, with the (wave-uniform-address) mask_int load issued concurrently with
// the bank-row load so both latencies overlap. Only lane 0 accumulates.
__device__ __forceinline__ void process_wave(const float2* __restrict__ bank2,
                                             const unsigned* __restrict__ m32,
                                             const unsigned char* __restrict__ m8,
                                             const unsigned* __restrict__ ent,
                                             int cnt, int flag, int b,
                                             float2 cv, float scale,
                                             unsigned lane, float& l1, float& l2) {
    for (int i = 0; i < cnt; ++i) {
        const unsigned n = ent[i];
        const float2 bv = bank2[(size_t)n * 64u + lane];
        const unsigned im = (flag == 0) ? m32[(size_t)b * NN + n]
                                        : (unsigned)m8[(size_t)b * NN + n];
        float d = fmaf(cv.x, bv.x, cv.y * bv.y);
#pragma unroll
        for (int off = 32; off > 0; off >>= 1) d += __shfl_down(d, off, 64);
        if (lane == 0) {
            const float e = __expf(d * scale);
            l1 += e;
            if (im) l2 += e;
        }
    }
}

// Fused scan + gather. Block = (slice s, row b). Hit lists are WAVE-private:
// no __syncthreads anywhere in the scan (only the single tail reduce barrier).
// All lanes stay active at loop level (load guards only), so the wave-level
// shuffles/ballots in the (never-taken-in-practice) flush path are safe.
__global__ __launch_bounds__(256) void la_fused(const float* __restrict__ codes,
                                                const float* __restrict__ bank,
                                                const void* __restrict__ mbg_v,
                                                const void* __restrict__ mint_v,
                                                unsigned* __restrict__ wsu) {
    __shared__ unsigned s_ent[4][CAPW];
    __shared__ unsigned s_cnt[4];
    __shared__ float s_red[8];

    const int t = threadIdx.x;
    const unsigned lane = (unsigned)(t & 63);
    const unsigned wid = (unsigned)(t >> 6);
    const int s = blockIdx.x;    // slice 0..7
    const int b = blockIdx.y;    // row 0..255

    // dtype flag from the 256 vote words (ballot -> wave-uniform, no barrier)
    const unsigned v4 = wsu[WS_VOTE + lane] | wsu[WS_VOTE + 64 + lane] |
                        wsu[WS_VOTE + 128 + lane] | wsu[WS_VOTE + 192 + lane];
    const int flag = (__ballot(v4 != 0u) != 0ull) ? 1 : 0;

    if (lane == 0) s_cnt[wid] = 0u;
    const float scale = ((const float*)wsu)[WS_SCALE + b];
    const float2 cv = ((const float2*)codes)[b * 64 + (int)lane];  // code frag in regs
    const float2* bank2 = (const float2*)bank;
    const unsigned* m32 = (const unsigned*)mint_v;
    const unsigned char* m8 = (const unsigned char*)mint_v;
    unsigned* ent = s_ent[wid];
    const int n_base = s * 25000;

    float l1 = 0.f, l2 = 0.f;

    if (flag == 0) {
        // int32 masks: slice = 6250 uint4 exactly; 13 iters x 512 uint4
        const uint4* row = (const uint4*)((const char*)mbg_v + (size_t)b * ((size_t)NN * 4)) + s * 6250;
        for (int it = 0; it < 13; ++it) {
            const int i0 = it * 512 + t;
            const int i1 = i0 + 256;
            uint4 v0 = make_uint4(0u, 0u, 0u, 0u), v1 = make_uint4(0u, 0u, 0u, 0u);
            if (i0 < 6250) v0 = row[i0];
            if (i1 < 6250) v1 = row[i1];
            const bool h0 = (v0.x | v0.y | v0.z | v0.w) != 0u;
            const bool h1 = (v1.x | v1.y | v1.z | v1.w) != 0u;
            if (__any((int)(h0 | h1))) {               // wave-skip all-zero chunks
                if (h0) {
                    const unsigned gw[4] = {v0.x, v0.y, v0.z, v0.w};
#pragma unroll
                    for (int j = 0; j < 4; ++j)
                        if (gw[j] != 0u) {
                            const unsigned pos = atomicAdd(&s_cnt[wid], 1u);
                            if (pos < CAPW) ent[pos] = (unsigned)(n_base + i0 * 4 + j);
                        }
                }
                if (h1) {
                    const unsigned gw[4] = {v1.x, v1.y, v1.z, v1.w};
#pragma unroll
                    for (int j = 0; j < 4; ++j)
                        if (gw[j] != 0u) {
                            const unsigned pos = atomicAdd(&s_cnt[wid], 1u);
                            if (pos < CAPW) ent[pos] = (unsigned)(n_base + i1 * 4 + j);
                        }
                }
                const int cnt = (int)*(volatile unsigned*)&s_cnt[wid];
                if (cnt >= FLUSHW) {                    // never in practice
                    process_wave(bank2, m32, m8, ent, cnt, flag, b, cv, scale, lane, l1, l2);
                    if (lane == 0) s_cnt[wid] = 0u;
                }
            }
        }
    } else {
        // bool-byte masks: slice = 3125 uint2 exactly (all 256 threads load);
        // 13 iters x 256 uint2, 8 bytes scanned per lane per iter.
        const uint2* row2 = (const uint2*)((const char*)mbg_v + (size_t)b * NN) + s * 3125;
        for (int it = 0; it < 13; ++it) {
            const int i0 = it * 256 + t;
            uint2 v = make_uint2(0u, 0u);
            if (i0 < 3125) v = row2[i0];
            const bool h = (v.x | v.y) != 0u;
            if (__any((int)h)) {                        // wave-skip all-zero chunks
                if (h) {
                    const unsigned gw[2] = {v.x, v.y};
#pragma unroll
                    for (int j = 0; j < 8; ++j)
                        if (((gw[j >> 2] >> ((j & 3) * 8)) & 0xffu) != 0u) {
                            const unsigned pos = atomicAdd(&s_cnt[wid], 1u);
                            if (pos < CAPW) ent[pos] = (unsigned)(n_base + i0 * 8 + j);
                        }
                }
                const int cnt = (int)*(volatile unsigned*)&s_cnt[wid];
                if (cnt >= FLUSHW) {                    // never in practice
                    process_wave(bank2, m32, m8, ent, cnt, flag, b, cv, scale, lane, l1, l2);
                    if (lane == 0) s_cnt[wid] = 0u;
                }
            }
        }
    }

    // ---- tail: drain this wave's list, one barrier, plain-store partials
    int cnt = (int)*(volatile unsigned*)&s_cnt[wid];
    if (cnt > CAPW) cnt = CAPW;
    process_wave(bank2, m32, m8, ent, cnt, flag, b, cv, scale, lane, l1, l2);

    if (lane == 0) { s_red[wid] = l1; s_red[4 + wid] = l2; }
    __syncthreads();
    if (t == 0) {
        float* wsf = (float*)wsu;
        wsf[WS_P1 + b * 8 + s] = s_red[0] + s_red[1] + s_red[2] + s_red[3];
        wsf[WS_P2 + b * 8 + s] = s_red[4] + s_red[5] + s_red[6] + s_red[7];
    }
}

__global__ __launch_bounds__(256) void la_final(const unsigned* __restrict__ wsu,
                                                float* __restrict__ out) {
    __shared__ float red[4];
    const int t = threadIdx.x;  // == row index, BB == 256
    const float* wsf = (const float*)wsu;
    float s1 = 0.f, s2 = 0.f;
#pragma unroll
    for (int s = 0; s < 8; ++s) {
        s1 += wsf[WS_P1 + t * 8 + s];
        s2 += wsf[WS_P2 + t * 8 + s];
    }
    float v = logf(s1) - logf(s2);
#pragma unroll
    for (int off = 32; off > 0; off >>= 1) v += __shfl_down(v, off, 64);
    if ((t & 63) == 0) red[t >> 6] = v;
    __syncthreads();
    if (t == 0) out[0] = (red[0] + red[1] + red[2] + red[3]) / (float)BB;
}

extern "C" void kernel_launch(void* const* d_in, const int* in_sizes, int n_in,
                              void* d_out, int out_size, void* d_ws, size_t ws_size,
                              hipStream_t stream) {
    const float* codes = (const float*)d_in[0];
    const float* bank  = (const float*)d_in[1];
    const void*  mbg   = d_in[2];
    const void*  mit   = d_in[3];

    unsigned* wsu = (unsigned*)d_ws;

    la_init<<<BB, 256, 0, stream>>>(codes, (const unsigned*)mbg, wsu);
    la_fused<<<dim3(8, BB), 256, 0, stream>>>(codes, bank, mbg, mit, wsu);
    la_final<<<1, 256, 0, stream>>>(wsu, (float*)d_out);
}